// Round 12
// baseline (353.828 us; speedup 1.0000x reference)
//
#include <hip/hip_runtime.h>
#include <hip/hip_fp16.h>

#define D 64         // hidden/output feature dim
#define SLICE 25000  // degree-histogram nodes per slice (100 KB LDS)
#define NBUCK 512    // dst buckets (dst>>8), 391 used
#define EPB 4096     // edges per k_bin block

typedef __attribute__((ext_vector_type(8))) short short8;   // 8 bf16 (4 VGPRs)
typedef __attribute__((ext_vector_type(4))) float floatx4;  // 4 fp32 acc

// ---------------------------------------------------------------------------
// LDS-sliced degree histogram (R10 verbatim, 1024-thread blocks).
// ---------------------------------------------------------------------------
__global__ __launch_bounds__(1024) void k_hist(const int* __restrict__ src,
                                               const int* __restrict__ dst,
                                               int* __restrict__ cnt_out,
                                               int* __restrict__ cnt_in,
                                               int E, int N) {
    __shared__ int h[SLICE];
    const int* idx = blockIdx.z ? dst : src;
    int* cnt       = blockIdx.z ? cnt_in : cnt_out;
    int lo = blockIdx.y * SLICE;
    int hi = min(lo + SLICE, N);
    int len = hi - lo;
    for (int i = threadIdx.x; i < len; i += 1024) h[i] = 0;
    __syncthreads();

    const int E4 = E >> 2;
    const int4* idx4 = (const int4*)idx;
    int stride = gridDim.x * 1024;
    for (int i = blockIdx.x * 1024 + threadIdx.x; i < E4; i += stride) {
        int4 v = idx4[i];
        if (v.x >= lo && v.x < hi) atomicAdd(&h[v.x - lo], 1);
        if (v.y >= lo && v.y < hi) atomicAdd(&h[v.y - lo], 1);
        if (v.z >= lo && v.z < hi) atomicAdd(&h[v.z - lo], 1);
        if (v.w >= lo && v.w < hi) atomicAdd(&h[v.w - lo], 1);
    }
    if (blockIdx.x == 0) {
        int e = E4 * 4 + threadIdx.x;
        if (e < E) {
            int v = idx[e];
            if (v >= lo && v < hi) atomicAdd(&h[v - lo], 1);
        }
    }
    __syncthreads();
    for (int i = threadIdx.x; i < len; i += 1024) {
        int c = h[i];
        if (c) atomicAdd(&cnt[lo + i], c);
    }
}

// ---- counts -> rsqrt(cnt + 1)  (the +1 is the self loop) ----
__global__ __launch_bounds__(256) void k_norm(const int* __restrict__ cnt,
                                              float* __restrict__ nrm, int n) {
    int i = blockIdx.x * 256 + threadIdx.x;
    if (i < n) nrm[i] = rsqrtf((float)cnt[i] + 1.0f);
}

// ---------------------------------------------------------------------------
// exclusive scan of cnt_in -> row_ptr  (R11 verbatim)
// ---------------------------------------------------------------------------
__global__ __launch_bounds__(256) void k_scan1(const int* __restrict__ in,
                                               int* __restrict__ out,
                                               int* __restrict__ partials, int n) {
    __shared__ int s[256];
    int tid = threadIdx.x;
    int base = blockIdx.x * 1024 + tid * 4;
    int v[4];
#pragma unroll
    for (int j = 0; j < 4; ++j) v[j] = (base + j < n) ? in[base + j] : 0;
    int l1 = v[0] + v[1];
    int l2 = l1 + v[2];
    int total = l2 + v[3];
    s[tid] = total;
    __syncthreads();
    for (int off = 1; off < 256; off <<= 1) {
        int add = (tid >= off) ? s[tid - off] : 0;
        __syncthreads();
        s[tid] += add;
        __syncthreads();
    }
    int excl = s[tid] - total;
    if (base + 0 < n) out[base + 0] = excl;
    if (base + 1 < n) out[base + 1] = excl + v[0];
    if (base + 2 < n) out[base + 2] = excl + l1;
    if (base + 3 < n) out[base + 3] = excl + l2;
    if (tid == 255) partials[blockIdx.x] = s[255];
}

__global__ void k_scan2(int* __restrict__ partials, int B,
                        int* __restrict__ row_ptr, int N, int E) {
    if (threadIdx.x == 0) {
        int run = 0;
        for (int i = 0; i < B; ++i) {
            int tmp = partials[i];
            partials[i] = run;
            run += tmp;
        }
    }
    if (threadIdx.x == 1) row_ptr[N] = E;  // sentinel
}

__global__ __launch_bounds__(256) void k_scan3(int* __restrict__ out,
                                               const int* __restrict__ partials, int n) {
    int off = partials[blockIdx.x];
    int base = blockIdx.x * 1024 + threadIdx.x * 4;
#pragma unroll
    for (int j = 0; j < 4; ++j)
        if (base + j < n) out[base + j] += off;
}

// ---------------------------------------------------------------------------
// Binned CSR build (R11 verbatim)
// ---------------------------------------------------------------------------
__global__ __launch_bounds__(256) void k_bin(const int* __restrict__ src,
                                             const int* __restrict__ dst,
                                             const int* __restrict__ row_ptr,
                                             int* __restrict__ bucket_cursor,
                                             unsigned long long* __restrict__ binned,
                                             int E) {
    __shared__ int cnt[NBUCK];
    __shared__ int bloc[NBUCK];
    __shared__ int lcur[NBUCK];
    __shared__ int gbase[NBUCK];
    __shared__ int ss[256];
    __shared__ unsigned long long stage[EPB];

    int tid = threadIdx.x;
    int start = blockIdx.x * EPB;
    int nloc = min(EPB, E - start);

    for (int i = tid; i < NBUCK; i += 256) cnt[i] = 0;
    __syncthreads();

#pragma unroll
    for (int r = 0; r < EPB / 256; ++r) {
        int idx = start + r * 256 + tid;
        if (idx < E) atomicAdd(&cnt[dst[idx] >> 8], 1);
    }
    __syncthreads();

    int a = cnt[2 * tid], b = cnt[2 * tid + 1];
    ss[tid] = a + b;
    __syncthreads();
    for (int off = 1; off < 256; off <<= 1) {
        int add = (tid >= off) ? ss[tid - off] : 0;
        __syncthreads();
        ss[tid] += add;
        __syncthreads();
    }
    int excl = ss[tid] - (a + b);
    bloc[2 * tid] = excl;           lcur[2 * tid] = excl;
    bloc[2 * tid + 1] = excl + a;   lcur[2 * tid + 1] = excl + a;
    __syncthreads();

    for (int bk = tid; bk < NBUCK; bk += 256) {
        int c = cnt[bk];
        gbase[bk] = c ? (atomicAdd(&bucket_cursor[bk], c) + row_ptr[bk << 8]) : 0;
    }
    __syncthreads();

#pragma unroll
    for (int r = 0; r < EPB / 256; ++r) {
        int idx = start + r * 256 + tid;
        if (idx < E) {
            int d = dst[idx];
            int p = atomicAdd(&lcur[d >> 8], 1);
            stage[p] = ((unsigned long long)(unsigned)d << 32) | (unsigned)src[idx];
        }
    }
    __syncthreads();

#pragma unroll
    for (int r = 0; r < EPB / 256; ++r) {
        int i = r * 256 + tid;
        if (i < nloc) {
            unsigned long long e = stage[i];
            int bk = (int)(e >> 40);
            binned[gbase[bk] + (i - bloc[bk])] = e;
        }
    }
}

__global__ __launch_bounds__(256) void k_bsort(const unsigned long long* __restrict__ binned,
                                               const int* __restrict__ row_ptr,
                                               int* __restrict__ csr, int N) {
    __shared__ int cur[256];
    int b = blockIdx.x;
    int n0 = b << 8;
    int tid = threadIdx.x;
    if (n0 + tid < N) cur[tid] = row_ptr[n0 + tid];
    __syncthreads();
    int base = row_ptr[n0];
    int c = row_ptr[min(n0 + 256, N)] - base;
    for (int k = tid; k < c; k += 256) {
        unsigned long long e = binned[base + k];
        int d = (int)(e >> 32);
        int s = (int)(e & 0xffffffffu);
        int p = atomicAdd(&cur[d - n0], 1);
        csr[p] = s;
    }
}

// ---------------------------------------------------------------------------
// MFMA dense layer via split-bf16 (R11 verbatim) — used for layer 1 only now.
// ---------------------------------------------------------------------------
template <int K>
__global__ __launch_bounds__(256) void k_gemm_mfma(const float* __restrict__ hsrc,
                                                   const float* __restrict__ W,   // [K,64] row-major
                                                   const float* __restrict__ norm_src,
                                                   __half* __restrict__ t, int N) {
    constexpr int NKI = K / 32;
    __shared__ short Whi[NKI * 2048];
    __shared__ short Wlo[NKI * 2048];
    int tid = threadIdx.x;

    for (int f = tid; f < K * 64; f += 256) {
        int n  = f & 15;
        int j  = (f >> 4) & 7;
        int q  = (f >> 7) & 3;
        int ct = (f >> 9) & 3;
        int ki = f >> 11;
        int k = ki * 32 + q * 8 + j;
        int c = ct * 16 + n;
        float w = W[k * 64 + c];
        unsigned u = __float_as_uint(w);
        float l = w - __uint_as_float(u & 0xffff0000u);
        int idx = (((ki * 4 + ct) * 16 + n) * 4 + q) * 8 + j;
        Whi[idx] = (short)(u >> 16);
        Wlo[idx] = (short)(__float_as_uint(l) >> 16);
    }
    __syncthreads();

    int wave = tid >> 6, lane = tid & 63;
    int q = lane >> 4, n = lane & 15;
    int r0 = blockIdx.x * 64 + wave * 16;
    int rowc = min(r0 + n, N - 1);

    floatx4 acc[4] = {{0.f,0.f,0.f,0.f},{0.f,0.f,0.f,0.f},
                      {0.f,0.f,0.f,0.f},{0.f,0.f,0.f,0.f}};

    for (int ki = 0; ki < NKI; ++ki) {
        const float* ap = hsrc + (long long)rowc * K + ki * 32 + q * 8;
        float4 a0 = *(const float4*)ap;
        float4 a1 = *(const float4*)(ap + 4);
        float av[8] = {a0.x, a0.y, a0.z, a0.w, a1.x, a1.y, a1.z, a1.w};
        short8 ahi, alo;
#pragma unroll
        for (int j = 0; j < 8; ++j) {
            unsigned u = __float_as_uint(av[j]);
            float l = av[j] - __uint_as_float(u & 0xffff0000u);
            ahi[j] = (short)(u >> 16);
            alo[j] = (short)(__float_as_uint(l) >> 16);
        }
#pragma unroll
        for (int ct = 0; ct < 4; ++ct) {
            int bidx = (((ki * 4 + ct) * 16 + n) * 4 + q) * 8;
            short8 bhi = *(const short8*)&Whi[bidx];
            short8 blo = *(const short8*)&Wlo[bidx];
            acc[ct] = __builtin_amdgcn_mfma_f32_16x16x32_bf16(ahi, bhi, acc[ct], 0, 0, 0);
            acc[ct] = __builtin_amdgcn_mfma_f32_16x16x32_bf16(ahi, blo, acc[ct], 0, 0, 0);
            acc[ct] = __builtin_amdgcn_mfma_f32_16x16x32_bf16(alo, bhi, acc[ct], 0, 0, 0);
        }
    }

#pragma unroll
    for (int reg = 0; reg < 4; ++reg) {
        int orow = r0 + q * 4 + reg;
        if (orow < N) {
            float nrm = norm_src[orow];
#pragma unroll
            for (int ct = 0; ct < 4; ++ct)
                t[(long long)orow * 64 + ct * 16 + n] = __float2half(acc[ct][reg] * nrm);
        }
    }
}

// ---------------------------------------------------------------------------
// FUSED layer-1 aggregate + layer-2 dense:
// phase 1: gather t -> h-row = relu(agg*norm_dst + b1), staged to LDS
//          ([64][68] fp32; +4 pad -> 2-way banks on the MFMA-phase reads)
// phase 2: split-bf16 MFMA with A from LDS; t2 = (h W2) * norm_src, fp16.
// Deletes the h global round-trip (51 MB) and the gemm2 dispatch.
// ---------------------------------------------------------------------------
__global__ __launch_bounds__(256) void k_aggmm(const int* __restrict__ row_ptr,
                                               const int* __restrict__ cnt,
                                               const int* __restrict__ csr,
                                               const __half* __restrict__ t,
                                               const float* __restrict__ norm_dst,
                                               const float* __restrict__ norm_src,
                                               const float* __restrict__ bias,   // b1
                                               const float* __restrict__ W,      // W2 [64,64]
                                               __half* __restrict__ t2, int N) {
    __shared__ float hs[64][68];
    __shared__ short Whi[4096];
    __shared__ short Wlo[4096];
    int tid = threadIdx.x;

    // stage + split + repack W2 (same fragment order as k_gemm_mfma, K=64)
    for (int f = tid; f < 64 * 64; f += 256) {
        int n  = f & 15;
        int j  = (f >> 4) & 7;
        int q  = (f >> 7) & 3;
        int ct = (f >> 9) & 3;
        int ki = f >> 11;
        int k = ki * 32 + q * 8 + j;
        int c = ct * 16 + n;
        float w = W[k * 64 + c];
        unsigned u = __float_as_uint(w);
        float l = w - __uint_as_float(u & 0xffff0000u);
        int idx = (((ki * 4 + ct) * 16 + n) * 4 + q) * 8 + j;
        Whi[idx] = (short)(u >> 16);
        Wlo[idx] = (short)(__float_as_uint(l) >> 16);
    }

    // ---- phase 1: gather (R8 pattern), 8 half-waves x 8 sequential nodes ----
    int hw = tid >> 5, lane = tid & 31;
    const __half2* t2r = (const __half2*)t;
    float2 bb = ((const float2*)bias)[lane];
    for (int r = 0; r < 8; ++r) {
        int il = r * 8 + hw;                 // 0..63 local row
        int i = blockIdx.x * 64 + il;
        if (i < N) {
            int start = row_ptr[i], c = cnt[i];
            float2 sf = __half22float2(t2r[i * 32 + lane]);
            float ax = sf.x, ay = sf.y;
            int j = 0;
            int pre = min(c, (4 - (start & 3)) & 3);
            for (; j < pre; ++j) {
                float2 f = __half22float2(t2r[csr[start + j] * 32 + lane]);
                ax += f.x; ay += f.y;
            }
            for (; j + 4 <= c; j += 4) {
                int4 s4 = *(const int4*)&csr[start + j];
                float2 f0 = __half22float2(t2r[s4.x * 32 + lane]);
                float2 f1 = __half22float2(t2r[s4.y * 32 + lane]);
                float2 f2 = __half22float2(t2r[s4.z * 32 + lane]);
                float2 f3 = __half22float2(t2r[s4.w * 32 + lane]);
                ax += (f0.x + f1.x) + (f2.x + f3.x);
                ay += (f0.y + f1.y) + (f2.y + f3.y);
            }
            for (; j < c; ++j) {
                float2 f = __half22float2(t2r[csr[start + j] * 32 + lane]);
                ax += f.x; ay += f.y;
            }
            float nrm = norm_dst[i];
            hs[il][lane * 2]     = fmaxf(fmaf(ax, nrm, bb.x), 0.f);
            hs[il][lane * 2 + 1] = fmaxf(fmaf(ay, nrm, bb.y), 0.f);
        }
    }
    __syncthreads();

    // ---- phase 2: MFMA, wave w handles local rows w*16..w*16+15 ----
    int wave = tid >> 6, lane64 = tid & 63;
    int q = lane64 >> 4, n = lane64 & 15;
    int m = wave * 16 + n;                   // A-row (local)
    floatx4 acc[4] = {{0.f,0.f,0.f,0.f},{0.f,0.f,0.f,0.f},
                      {0.f,0.f,0.f,0.f},{0.f,0.f,0.f,0.f}};
#pragma unroll
    for (int ki = 0; ki < 2; ++ki) {
        const float* ap = &hs[m][ki * 32 + q * 8];
        float4 a0 = *(const float4*)ap;
        float4 a1 = *(const float4*)(ap + 4);
        float av[8] = {a0.x, a0.y, a0.z, a0.w, a1.x, a1.y, a1.z, a1.w};
        short8 ahi, alo;
#pragma unroll
        for (int j = 0; j < 8; ++j) {
            unsigned u = __float_as_uint(av[j]);
            float l = av[j] - __uint_as_float(u & 0xffff0000u);
            ahi[j] = (short)(u >> 16);
            alo[j] = (short)(__float_as_uint(l) >> 16);
        }
#pragma unroll
        for (int ct = 0; ct < 4; ++ct) {
            int bidx = (((ki * 4 + ct) * 16 + n) * 4 + q) * 8;
            short8 bhi = *(const short8*)&Whi[bidx];
            short8 blo = *(const short8*)&Wlo[bidx];
            acc[ct] = __builtin_amdgcn_mfma_f32_16x16x32_bf16(ahi, bhi, acc[ct], 0, 0, 0);
            acc[ct] = __builtin_amdgcn_mfma_f32_16x16x32_bf16(ahi, blo, acc[ct], 0, 0, 0);
            acc[ct] = __builtin_amdgcn_mfma_f32_16x16x32_bf16(alo, bhi, acc[ct], 0, 0, 0);
        }
    }
#pragma unroll
    for (int reg = 0; reg < 4; ++reg) {
        int orow = blockIdx.x * 64 + wave * 16 + q * 4 + reg;
        if (orow < N) {
            float nrm = norm_src[orow];
#pragma unroll
            for (int ct = 0; ct < 4; ++ct)
                t2[(long long)orow * 64 + ct * 16 + n] = __float2half(acc[ct][reg] * nrm);
        }
    }
}

// ---------------------------------------------------------------------------
// gather-aggregate (R8/R11 verbatim) — layer 2 only now.
// ---------------------------------------------------------------------------
__global__ __launch_bounds__(256) void k_agg(const int* __restrict__ row_ptr,
                                             const int* __restrict__ cnt,
                                             const int* __restrict__ csr,
                                             const __half* __restrict__ t,
                                             const float* __restrict__ norm_dst,
                                             const float* __restrict__ bias,
                                             float* __restrict__ out, int N, int do_relu) {
    int tid = threadIdx.x;
    int half_id = tid >> 5;
    int lane = tid & 31;
    int i = blockIdx.x * 8 + half_id;
    if (i >= N) return;
    const __half2* t2 = (const __half2*)t;
    int start = row_ptr[i], c = cnt[i];

    float2 sf = __half22float2(t2[i * 32 + lane]);
    float ax = sf.x, ay = sf.y;

    int j = 0;
    int pre = min(c, (4 - (start & 3)) & 3);
    for (; j < pre; ++j) {
        float2 f = __half22float2(t2[csr[start + j] * 32 + lane]);
        ax += f.x; ay += f.y;
    }
    for (; j + 4 <= c; j += 4) {
        int4 s4 = *(const int4*)&csr[start + j];
        float2 f0 = __half22float2(t2[s4.x * 32 + lane]);
        float2 f1 = __half22float2(t2[s4.y * 32 + lane]);
        float2 f2 = __half22float2(t2[s4.z * 32 + lane]);
        float2 f3 = __half22float2(t2[s4.w * 32 + lane]);
        ax += (f0.x + f1.x) + (f2.x + f3.x);
        ay += (f0.y + f1.y) + (f2.y + f3.y);
    }
    for (; j < c; ++j) {
        float2 f = __half22float2(t2[csr[start + j] * 32 + lane]);
        ax += f.x; ay += f.y;
    }

    float nrm = norm_dst[i];
    float2 bb = ((const float2*)bias)[lane];
    float vx = fmaf(ax, nrm, bb.x);
    float vy = fmaf(ay, nrm, bb.y);
    if (do_relu) { vx = fmaxf(vx, 0.f); vy = fmaxf(vy, 0.f); }
    float2 o; o.x = vx; o.y = vy;
    ((float2*)out)[i * 32 + lane] = o;
}

extern "C" void kernel_launch(void* const* d_in, const int* in_sizes, int n_in,
                              void* d_out, int out_size, void* d_ws, size_t ws_size,
                              hipStream_t stream) {
    const float* x   = (const float*)d_in[0];
    const int*   src = (const int*)d_in[1];
    const int*   dst = (const int*)d_in[2];
    const float* W1  = (const float*)d_in[3];
    const float* b1  = (const float*)d_in[4];
    const float* W2  = (const float*)d_in[5];
    const float* b2  = (const float*)d_in[6];
    float* out = (float*)d_out;

    const int N = in_sizes[0] / 128;
    const int E = in_sizes[1];

    // workspace layout (4-byte units):
    int*   cnt_out  = (int*)d_ws;                // N
    int*   cnt_in   = cnt_out + N;               // N   (one memset covers both)
    int*   row_ptr  = cnt_in + N;                // N+1 (sentinel row_ptr[N]=E)
    int*   partials = row_ptr + N + 1;           // 1024
    float* norm_src = (float*)(partials + 1024); // N
    float* norm_dst = norm_src + N;              // N
    // tbase: 256B-aligned (R11 fix — misalignment doubles gather FETCH).
    long long toff = (5LL * N + 1025 + 63) & ~63LL;
    float* tbase    = (float*)d_ws + toff;       // N*64 fp32-sized region
    float* hreg     = tbase + (long long)N * D;  // N*64 fp32-sized region (holds t2 now)
    int*   csr      = (int*)(hreg + (long long)N * D); // E
    int*   bucket_cursor = csr + E;              // NBUCK
    __half* t_h  = (__half*)tbase;               // layer-1 messages, [N x 64] fp16
    __half* t2_h = (__half*)hreg;                // layer-2 messages, [N x 64] fp16 (aligned)
    unsigned long long* binned = (unsigned long long*)tbase;  // dead before gemm1

    const int B = (N + 1023) / 1024;
    const int NS = (N + SLICE - 1) / SLICE;
    const int NB = (N + 255) / 256;
    const int NBK = (E + EPB - 1) / EPB;

    hipMemsetAsync(cnt_out, 0, (size_t)2 * N * sizeof(int), stream);
    hipMemsetAsync(bucket_cursor, 0, (size_t)NBUCK * sizeof(int), stream);

    k_hist<<<dim3(8, NS, 2), 1024, 0, stream>>>(src, dst, cnt_out, cnt_in, E, N);
    k_norm<<<(2 * N + 255) / 256, 256, 0, stream>>>(cnt_out, norm_src, 2 * N);

    k_scan1<<<B, 256, 0, stream>>>(cnt_in, row_ptr, partials, N);
    k_scan2<<<1, 64, 0, stream>>>(partials, B, row_ptr, N, E);
    k_scan3<<<B, 256, 0, stream>>>(row_ptr, partials, N);

    k_bin<<<NBK, 256, 0, stream>>>(src, dst, row_ptr, bucket_cursor, binned, E);
    k_bsort<<<NB, 256, 0, stream>>>(binned, row_ptr, csr, N);

    // layer 1 dense: t = (x W1) * norm_src
    k_gemm_mfma<128><<<(N + 63) / 64, 256, 0, stream>>>(x, W1, norm_src, t_h, N);
    // fused layer-1 aggregate + layer-2 dense: t2 = (relu(agg(t)*norm_dst+b1) W2) * norm_src
    k_aggmm<<<(N + 63) / 64, 256, 0, stream>>>(row_ptr, cnt_in, csr, t_h,
                                               norm_dst, norm_src, b1, W2, t2_h, N);
    // layer-2 aggregate: out = agg(t2)*norm_dst + b2
    k_agg<<<(N + 7) / 8, 256, 0, stream>>>(row_ptr, cnt_in, csr, t2_h, norm_dst, b2, out, N, 0);
}

// Round 13
// 294.647 us; speedup vs baseline: 1.2009x; 1.2009x over previous
//
#include <hip/hip_runtime.h>
#include <hip/hip_fp16.h>

#define D 64         // hidden/output feature dim
#define SLICE 25000  // degree-histogram nodes per slice (100 KB LDS)
#define NBUCK 512    // dst buckets (dst>>8), 391 used
#define EPB 4096     // edges per k_bin block

typedef __attribute__((ext_vector_type(8))) short short8;   // 8 bf16 (4 VGPRs)
typedef __attribute__((ext_vector_type(4))) float floatx4;  // 4 fp32 acc

// ---------------------------------------------------------------------------
// LDS-sliced degree histogram (R10 verbatim, 1024-thread blocks).
// ---------------------------------------------------------------------------
__global__ __launch_bounds__(1024) void k_hist(const int* __restrict__ src,
                                               const int* __restrict__ dst,
                                               int* __restrict__ cnt_out,
                                               int* __restrict__ cnt_in,
                                               int E, int N) {
    __shared__ int h[SLICE];
    const int* idx = blockIdx.z ? dst : src;
    int* cnt       = blockIdx.z ? cnt_in : cnt_out;
    int lo = blockIdx.y * SLICE;
    int hi = min(lo + SLICE, N);
    int len = hi - lo;
    for (int i = threadIdx.x; i < len; i += 1024) h[i] = 0;
    __syncthreads();

    const int E4 = E >> 2;
    const int4* idx4 = (const int4*)idx;
    int stride = gridDim.x * 1024;
    for (int i = blockIdx.x * 1024 + threadIdx.x; i < E4; i += stride) {
        int4 v = idx4[i];
        if (v.x >= lo && v.x < hi) atomicAdd(&h[v.x - lo], 1);
        if (v.y >= lo && v.y < hi) atomicAdd(&h[v.y - lo], 1);
        if (v.z >= lo && v.z < hi) atomicAdd(&h[v.z - lo], 1);
        if (v.w >= lo && v.w < hi) atomicAdd(&h[v.w - lo], 1);
    }
    if (blockIdx.x == 0) {
        int e = E4 * 4 + threadIdx.x;
        if (e < E) {
            int v = idx[e];
            if (v >= lo && v < hi) atomicAdd(&h[v - lo], 1);
        }
    }
    __syncthreads();
    for (int i = threadIdx.x; i < len; i += 1024) {
        int c = h[i];
        if (c) atomicAdd(&cnt[lo + i], c);
    }
}

// ---- counts -> rsqrt(cnt + 1)  (the +1 is the self loop) ----
__global__ __launch_bounds__(256) void k_norm(const int* __restrict__ cnt,
                                              float* __restrict__ nrm, int n) {
    int i = blockIdx.x * 256 + threadIdx.x;
    if (i < n) nrm[i] = rsqrtf((float)cnt[i] + 1.0f);
}

// ---------------------------------------------------------------------------
// exclusive scan of cnt_in -> row_ptr
// ---------------------------------------------------------------------------
__global__ __launch_bounds__(256) void k_scan1(const int* __restrict__ in,
                                               int* __restrict__ out,
                                               int* __restrict__ partials, int n) {
    __shared__ int s[256];
    int tid = threadIdx.x;
    int base = blockIdx.x * 1024 + tid * 4;
    int v[4];
#pragma unroll
    for (int j = 0; j < 4; ++j) v[j] = (base + j < n) ? in[base + j] : 0;
    int l1 = v[0] + v[1];
    int l2 = l1 + v[2];
    int total = l2 + v[3];
    s[tid] = total;
    __syncthreads();
    for (int off = 1; off < 256; off <<= 1) {
        int add = (tid >= off) ? s[tid - off] : 0;
        __syncthreads();
        s[tid] += add;
        __syncthreads();
    }
    int excl = s[tid] - total;
    if (base + 0 < n) out[base + 0] = excl;
    if (base + 1 < n) out[base + 1] = excl + v[0];
    if (base + 2 < n) out[base + 2] = excl + l1;
    if (base + 3 < n) out[base + 3] = excl + l2;
    if (tid == 255) partials[blockIdx.x] = s[255];
}

// parallel scan of block partials (B <= 256) + row_ptr sentinel
__global__ __launch_bounds__(256) void k_scan2(int* __restrict__ partials, int B,
                                               int* __restrict__ row_ptr, int N, int E) {
    __shared__ int s[256];
    int tid = threadIdx.x;
    int v = (tid < B) ? partials[tid] : 0;
    s[tid] = v;
    __syncthreads();
    for (int off = 1; off < 256; off <<= 1) {
        int add = (tid >= off) ? s[tid - off] : 0;
        __syncthreads();
        s[tid] += add;
        __syncthreads();
    }
    if (tid < B) partials[tid] = s[tid] - v;   // exclusive
    if (tid == 0) row_ptr[N] = E;              // sentinel
}

__global__ __launch_bounds__(256) void k_scan3(int* __restrict__ out,
                                               const int* __restrict__ partials, int n) {
    int off = partials[blockIdx.x];
    int base = blockIdx.x * 1024 + threadIdx.x * 4;
#pragma unroll
    for (int j = 0; j < 4; ++j)
        if (base + j < n) out[base + j] += off;
}

// ---------------------------------------------------------------------------
// Binned CSR build (R11 verbatim)
// ---------------------------------------------------------------------------
__global__ __launch_bounds__(256) void k_bin(const int* __restrict__ src,
                                             const int* __restrict__ dst,
                                             const int* __restrict__ row_ptr,
                                             int* __restrict__ bucket_cursor,
                                             unsigned long long* __restrict__ binned,
                                             int E) {
    __shared__ int cnt[NBUCK];
    __shared__ int bloc[NBUCK];
    __shared__ int lcur[NBUCK];
    __shared__ int gbase[NBUCK];
    __shared__ int ss[256];
    __shared__ unsigned long long stage[EPB];

    int tid = threadIdx.x;
    int start = blockIdx.x * EPB;
    int nloc = min(EPB, E - start);

    for (int i = tid; i < NBUCK; i += 256) cnt[i] = 0;
    __syncthreads();

#pragma unroll
    for (int r = 0; r < EPB / 256; ++r) {
        int idx = start + r * 256 + tid;
        if (idx < E) atomicAdd(&cnt[dst[idx] >> 8], 1);
    }
    __syncthreads();

    int a = cnt[2 * tid], b = cnt[2 * tid + 1];
    ss[tid] = a + b;
    __syncthreads();
    for (int off = 1; off < 256; off <<= 1) {
        int add = (tid >= off) ? ss[tid - off] : 0;
        __syncthreads();
        ss[tid] += add;
        __syncthreads();
    }
    int excl = ss[tid] - (a + b);
    bloc[2 * tid] = excl;           lcur[2 * tid] = excl;
    bloc[2 * tid + 1] = excl + a;   lcur[2 * tid + 1] = excl + a;
    __syncthreads();

    for (int bk = tid; bk < NBUCK; bk += 256) {
        int c = cnt[bk];
        gbase[bk] = c ? (atomicAdd(&bucket_cursor[bk], c) + row_ptr[bk << 8]) : 0;
    }
    __syncthreads();

#pragma unroll
    for (int r = 0; r < EPB / 256; ++r) {
        int idx = start + r * 256 + tid;
        if (idx < E) {
            int d = dst[idx];
            int p = atomicAdd(&lcur[d >> 8], 1);
            stage[p] = ((unsigned long long)(unsigned)d << 32) | (unsigned)src[idx];
        }
    }
    __syncthreads();

#pragma unroll
    for (int r = 0; r < EPB / 256; ++r) {
        int i = r * 256 + tid;
        if (i < nloc) {
            unsigned long long e = stage[i];
            int bk = (int)(e >> 40);
            binned[gbase[bk] + (i - bloc[bk])] = e;
        }
    }
}

__global__ __launch_bounds__(256) void k_bsort(const unsigned long long* __restrict__ binned,
                                               const int* __restrict__ row_ptr,
                                               int* __restrict__ csr, int N) {
    __shared__ int cur[256];
    int b = blockIdx.x;
    int n0 = b << 8;
    int tid = threadIdx.x;
    if (n0 + tid < N) cur[tid] = row_ptr[n0 + tid];
    __syncthreads();
    int base = row_ptr[n0];
    int c = row_ptr[min(n0 + 256, N)] - base;
    for (int k = tid; k < c; k += 256) {
        unsigned long long e = binned[base + k];
        int d = (int)(e >> 32);
        int s = (int)(e & 0xffffffffu);
        int p = atomicAdd(&cur[d - n0], 1);
        csr[p] = s;
    }
}

// ---------------------------------------------------------------------------
// MFMA dense layer via split-bf16 (R11 verbatim)
// ---------------------------------------------------------------------------
template <int K>
__global__ __launch_bounds__(256) void k_gemm_mfma(const float* __restrict__ hsrc,
                                                   const float* __restrict__ W,   // [K,64] row-major
                                                   const float* __restrict__ norm_src,
                                                   __half* __restrict__ t, int N) {
    constexpr int NKI = K / 32;
    __shared__ short Whi[NKI * 2048];
    __shared__ short Wlo[NKI * 2048];
    int tid = threadIdx.x;

    for (int f = tid; f < K * 64; f += 256) {
        int n  = f & 15;
        int j  = (f >> 4) & 7;
        int q  = (f >> 7) & 3;
        int ct = (f >> 9) & 3;
        int ki = f >> 11;
        int k = ki * 32 + q * 8 + j;
        int c = ct * 16 + n;
        float w = W[k * 64 + c];
        unsigned u = __float_as_uint(w);
        float l = w - __uint_as_float(u & 0xffff0000u);
        int idx = (((ki * 4 + ct) * 16 + n) * 4 + q) * 8 + j;
        Whi[idx] = (short)(u >> 16);
        Wlo[idx] = (short)(__float_as_uint(l) >> 16);
    }
    __syncthreads();

    int wave = tid >> 6, lane = tid & 63;
    int q = lane >> 4, n = lane & 15;
    int r0 = blockIdx.x * 64 + wave * 16;
    int rowc = min(r0 + n, N - 1);

    floatx4 acc[4] = {{0.f,0.f,0.f,0.f},{0.f,0.f,0.f,0.f},
                      {0.f,0.f,0.f,0.f},{0.f,0.f,0.f,0.f}};

    for (int ki = 0; ki < NKI; ++ki) {
        const float* ap = hsrc + (long long)rowc * K + ki * 32 + q * 8;
        float4 a0 = *(const float4*)ap;
        float4 a1 = *(const float4*)(ap + 4);
        float av[8] = {a0.x, a0.y, a0.z, a0.w, a1.x, a1.y, a1.z, a1.w};
        short8 ahi, alo;
#pragma unroll
        for (int j = 0; j < 8; ++j) {
            unsigned u = __float_as_uint(av[j]);
            float l = av[j] - __uint_as_float(u & 0xffff0000u);
            ahi[j] = (short)(u >> 16);
            alo[j] = (short)(__float_as_uint(l) >> 16);
        }
#pragma unroll
        for (int ct = 0; ct < 4; ++ct) {
            int bidx = (((ki * 4 + ct) * 16 + n) * 4 + q) * 8;
            short8 bhi = *(const short8*)&Whi[bidx];
            short8 blo = *(const short8*)&Wlo[bidx];
            acc[ct] = __builtin_amdgcn_mfma_f32_16x16x32_bf16(ahi, bhi, acc[ct], 0, 0, 0);
            acc[ct] = __builtin_amdgcn_mfma_f32_16x16x32_bf16(ahi, blo, acc[ct], 0, 0, 0);
            acc[ct] = __builtin_amdgcn_mfma_f32_16x16x32_bf16(alo, bhi, acc[ct], 0, 0, 0);
        }
    }

#pragma unroll
    for (int reg = 0; reg < 4; ++reg) {
        int orow = r0 + q * 4 + reg;
        if (orow < N) {
            float nrm = norm_src[orow];
#pragma unroll
            for (int ct = 0; ct < 4; ++ct)
                t[(long long)orow * 64 + ct * 16 + n] = __float2half(acc[ct][reg] * nrm);
        }
    }
}

// ---------------------------------------------------------------------------
// gather-aggregate: wave = 2 nodes (32 lanes each); lane = channel-pair.
// 8-deep unroll: two broadcast int4 index loads -> 8 outstanding row gathers
// per half-wave (R8 had 4) to better hide L3 latency.
// ---------------------------------------------------------------------------
__global__ __launch_bounds__(256) void k_agg(const int* __restrict__ row_ptr,
                                             const int* __restrict__ cnt,
                                             const int* __restrict__ csr,
                                             const __half* __restrict__ t,
                                             const float* __restrict__ norm_dst,
                                             const float* __restrict__ bias,
                                             float* __restrict__ out, int N, int do_relu) {
    int tid = threadIdx.x;
    int half_id = tid >> 5;
    int lane = tid & 31;
    int i = blockIdx.x * 8 + half_id;
    if (i >= N) return;
    const __half2* t2 = (const __half2*)t;
    int start = row_ptr[i], c = cnt[i];

    float2 sf = __half22float2(t2[i * 32 + lane]);
    float ax = sf.x, ay = sf.y;

    int j = 0;
    int pre = min(c, (4 - (start & 3)) & 3);   // align csr pointer to 16B
    for (; j < pre; ++j) {
        float2 f = __half22float2(t2[csr[start + j] * 32 + lane]);
        ax += f.x; ay += f.y;
    }
    for (; j + 8 <= c; j += 8) {
        int4 s4 = *(const int4*)&csr[start + j];
        int4 s5 = *(const int4*)&csr[start + j + 4];
        float2 f0 = __half22float2(t2[s4.x * 32 + lane]);
        float2 f1 = __half22float2(t2[s4.y * 32 + lane]);
        float2 f2 = __half22float2(t2[s4.z * 32 + lane]);
        float2 f3 = __half22float2(t2[s4.w * 32 + lane]);
        float2 f4 = __half22float2(t2[s5.x * 32 + lane]);
        float2 f5 = __half22float2(t2[s5.y * 32 + lane]);
        float2 f6 = __half22float2(t2[s5.z * 32 + lane]);
        float2 f7 = __half22float2(t2[s5.w * 32 + lane]);
        ax += ((f0.x + f1.x) + (f2.x + f3.x)) + ((f4.x + f5.x) + (f6.x + f7.x));
        ay += ((f0.y + f1.y) + (f2.y + f3.y)) + ((f4.y + f5.y) + (f6.y + f7.y));
    }
    for (; j + 4 <= c; j += 4) {
        int4 s4 = *(const int4*)&csr[start + j];
        float2 f0 = __half22float2(t2[s4.x * 32 + lane]);
        float2 f1 = __half22float2(t2[s4.y * 32 + lane]);
        float2 f2 = __half22float2(t2[s4.z * 32 + lane]);
        float2 f3 = __half22float2(t2[s4.w * 32 + lane]);
        ax += (f0.x + f1.x) + (f2.x + f3.x);
        ay += (f0.y + f1.y) + (f2.y + f3.y);
    }
    for (; j < c; ++j) {
        float2 f = __half22float2(t2[csr[start + j] * 32 + lane]);
        ax += f.x; ay += f.y;
    }

    float nrm = norm_dst[i];
    float2 bb = ((const float2*)bias)[lane];
    float vx = fmaf(ax, nrm, bb.x);
    float vy = fmaf(ay, nrm, bb.y);
    if (do_relu) { vx = fmaxf(vx, 0.f); vy = fmaxf(vy, 0.f); }
    float2 o; o.x = vx; o.y = vy;
    ((float2*)out)[i * 32 + lane] = o;
}

extern "C" void kernel_launch(void* const* d_in, const int* in_sizes, int n_in,
                              void* d_out, int out_size, void* d_ws, size_t ws_size,
                              hipStream_t stream) {
    const float* x   = (const float*)d_in[0];
    const int*   src = (const int*)d_in[1];
    const int*   dst = (const int*)d_in[2];
    const float* W1  = (const float*)d_in[3];
    const float* b1  = (const float*)d_in[4];
    const float* W2  = (const float*)d_in[5];
    const float* b2  = (const float*)d_in[6];
    float* out = (float*)d_out;

    const int N = in_sizes[0] / 128;
    const int E = in_sizes[1];

    // workspace layout (4-byte units):
    int*   cnt_out  = (int*)d_ws;                // N
    int*   cnt_in   = cnt_out + N;               // N   (one memset covers both)
    int*   row_ptr  = cnt_in + N;                // N+1 (sentinel row_ptr[N]=E)
    int*   partials = row_ptr + N + 1;           // 1024
    float* norm_src = (float*)(partials + 1024); // N
    float* norm_dst = norm_src + N;              // N
    // tbase: 256B-aligned (R11 fix — misalignment doubles gather FETCH).
    long long toff = (5LL * N + 1025 + 63) & ~63LL;
    float* tbase    = (float*)d_ws + toff;       // N*64 fp32 region (fp16 uses half)
    float* h        = tbase + (long long)N * D;  // N*64 fp32 (stays aligned)
    int*   csr      = (int*)(h + (long long)N * D); // E
    int*   bucket_cursor = csr + E;              // NBUCK
    __half* t_h = (__half*)tbase;                // interleaved [N x 64] fp16
    unsigned long long* binned = (unsigned long long*)tbase;  // dead before gemm1

    const int B = (N + 1023) / 1024;
    const int NS = (N + SLICE - 1) / SLICE;
    const int NB = (N + 255) / 256;
    const int NBK = (E + EPB - 1) / EPB;

    hipMemsetAsync(cnt_out, 0, (size_t)2 * N * sizeof(int), stream);
    hipMemsetAsync(bucket_cursor, 0, (size_t)NBUCK * sizeof(int), stream);

    k_hist<<<dim3(8, NS, 2), 1024, 0, stream>>>(src, dst, cnt_out, cnt_in, E, N);
    k_norm<<<(2 * N + 255) / 256, 256, 0, stream>>>(cnt_out, norm_src, 2 * N);

    k_scan1<<<B, 256, 0, stream>>>(cnt_in, row_ptr, partials, N);
    k_scan2<<<1, 256, 0, stream>>>(partials, B, row_ptr, N, E);
    k_scan3<<<B, 256, 0, stream>>>(row_ptr, partials, N);

    k_bin<<<NBK, 256, 0, stream>>>(src, dst, row_ptr, bucket_cursor, binned, E);
    k_bsort<<<NB, 256, 0, stream>>>(binned, row_ptr, csr, N);

    // layer 1: t = (x W1) * norm_src ; h = relu(agg * norm_dst + b1)
    k_gemm_mfma<128><<<(N + 63) / 64, 256, 0, stream>>>(x, W1, norm_src, t_h, N);
    k_agg<<<(N + 7) / 8, 256, 0, stream>>>(row_ptr, cnt_in, csr, t_h, norm_dst, b1, h, N, 1);

    // layer 2: t = (h W2) * norm_src ; out = agg * norm_dst + b2
    k_gemm_mfma<64><<<(N + 63) / 64, 256, 0, stream>>>(h, W2, norm_src, t_h, N);
    k_agg<<<(N + 7) / 8, 256, 0, stream>>>(row_ptr, cnt_in, csr, t_h, norm_dst, b2, out, N, 0);
}